// Round 1
// baseline (1232.168 us; speedup 1.0000x reference)
//
#include <hip/hip_runtime.h>
#include <math.h>

// ---------------- constants ----------------
#define B 32
#define SEQ 512
#define NTOK 680           // 512+128+32+8
#define DM 256
#define HEADS 4
#define DK 64
#define FF 512
#define NROWS (B*NTOK)     // 21760

// ---------------- embedding ----------------
// one block per (b,s), 256 threads = d
__global__ __launch_bounds__(256) void emb_kernel(
    const float* __restrict__ x_enc, const float* __restrict__ x_mark,
    const float* __restrict__ W_val, const float* __restrict__ W_time,
    const float* __restrict__ b_time, float* __restrict__ X)
{
    int bs = blockIdx.x;
    int b = bs >> 9, s = bs & 511;
    int d = threadIdx.x;
    int sm1 = (s + 511) & 511, sp1 = (s + 1) & 511;
    float x0 = x_enc[b*512 + sm1];
    float x1 = x_enc[b*512 + s];
    float x2 = x_enc[b*512 + sp1];
    float val = x0 * W_val[d*3+0] + x1 * W_val[d*3+1] + x2 * W_val[d*3+2];
    const float* mk = &x_mark[(size_t)bs*4];
    float tm = mk[0]*W_time[d] + mk[1]*W_time[256+d] + mk[2]*W_time[512+d] + mk[3]*W_time[768+d];
    // positional encoding: div = exp(-(2i)*ln(10000)/256), even->sin, odd->cos
    int i2 = d & ~1;
    float div = expf((float)i2 * (-9.210340371976184f / 256.0f));
    float ang = (float)s * div;
    float pe = (d & 1) ? cosf(ang) : sinf(ang);
    X[((size_t)(b*NTOK + s))*DM + d] = val + tm + b_time[d] + pe;
}

// ---------------- CSCM down-projection: emb[.,256] @ W_down[256,64] ----------------
// block handles 4 positions; 256 threads: r = t>>6 (position in group), c = t&63 (out ch)
__global__ __launch_bounds__(256) void down_kernel(
    const float* __restrict__ X, const float* __restrict__ W_down,
    const float* __restrict__ b_down, float* __restrict__ Td)
{
    __shared__ float rows[4][256];
    int g = blockIdx.x;
    int t = threadIdx.x;
    int r = t >> 6, c = t & 63;
    int bs = g*4 + r;
    int xrow = (bs >> 9)*NTOK + (bs & 511);
    for (int u = c; u < 256; u += 64) rows[r][u] = X[(size_t)xrow*DM + u];
    __syncthreads();
    float acc = b_down[c];
    #pragma unroll 8
    for (int k = 0; k < 256; ++k) acc = fmaf(rows[r][k], W_down[k*64 + c], acc);
    Td[(size_t)bs*64 + c] = acc;
}

// ---------------- CSCM strided conv (k=4, s=4) + BN affine + ELU ----------------
// input rows laid out [.. , 64] position-major; one block per output position, 64 threads = out ch
__global__ __launch_bounds__(64) void conv_kernel(
    const float* __restrict__ in, int inRPB, int inOff,
    float* __restrict__ Pool, int outOff, int Lout,
    const float* __restrict__ W_conv, const float* __restrict__ b_conv,
    const float* __restrict__ bn_g, const float* __restrict__ bn_b, int sc)
{
    __shared__ float lds[256];
    int blk = blockIdx.x;
    int b = blk / Lout, p = blk % Lout;
    int t = threadIdx.x;
    for (int u = t; u < 256; u += 64)
        lds[u] = in[((size_t)(b*inRPB + inOff + p*4 + (u >> 6)))*64 + (u & 63)];
    __syncthreads();
    float acc = b_conv[sc*64 + t];
    const float* w = &W_conv[(size_t)(sc*64 + t)*256];   // [ci][tap], 4 taps per ci
    #pragma unroll 4
    for (int ci = 0; ci < 64; ++ci) {
        #pragma unroll
        for (int tap = 0; tap < 4; ++tap)
            acc = fmaf(lds[tap*64 + ci], w[ci*4 + tap], acc);
    }
    float v = acc * bn_g[sc*64 + t] + bn_b[sc*64 + t];
    v = v > 0.f ? v : expm1f(v);                         // ELU (alpha=1)
    Pool[((size_t)(b*168 + outOff + p))*64 + t] = v;
}

// ---------------- CSCM up-projection: Pool[.,64] @ W_up[64,256] ----------------
__global__ __launch_bounds__(256) void up_kernel(
    const float* __restrict__ Pool, const float* __restrict__ W_up,
    const float* __restrict__ b_up, float* __restrict__ X)
{
    __shared__ float row[64];
    int blk = blockIdx.x;               // b*168 + p
    int b = blk / 168, p = blk % 168;
    int d = threadIdx.x;
    if (d < 64) row[d] = Pool[(size_t)blk*64 + d];
    __syncthreads();
    float acc = b_up[d];
    #pragma unroll 8
    for (int k = 0; k < 64; ++k) acc = fmaf(row[k], W_up[k*256 + d], acc);
    X[((size_t)(b*NTOK + 512 + p))*DM + d] = acc;
}

// ---------------- LayerNorm (optional residual add), in-place on X ----------------
__global__ __launch_bounds__(256) void ln_kernel(
    float* __restrict__ X, const float* __restrict__ add,
    const float* __restrict__ g, const float* __restrict__ bta)
{
    __shared__ float sm[4];
    int r = blockIdx.x, t = threadIdx.x;
    float v = X[(size_t)r*DM + t];
    if (add) v += add[(size_t)r*DM + t];
    float s = v;
    #pragma unroll
    for (int o = 32; o; o >>= 1) s += __shfl_xor(s, o);
    if ((t & 63) == 0) sm[t >> 6] = s;
    __syncthreads();
    float mean = (sm[0]+sm[1]+sm[2]+sm[3]) * (1.0f/256.0f);
    __syncthreads();
    float dv = v - mean;
    float q = dv*dv;
    #pragma unroll
    for (int o = 32; o; o >>= 1) q += __shfl_xor(q, o);
    if ((t & 63) == 0) sm[t >> 6] = q;
    __syncthreads();
    float var = (sm[0]+sm[1]+sm[2]+sm[3]) * (1.0f/256.0f);
    X[(size_t)r*DM + t] = dv * rsqrtf(var + 1e-5f) * g[t] + bta[t];
}

// ---------------- neighbor lists from the Pyraformer mask ----------------
// sizes {512,128,32,8}, starts {0,512,640,672}; max degree is 10 (<=16 slots)
__device__ __forceinline__ int scale_of(int p) {
    return p < 512 ? 0 : (p < 640 ? 1 : (p < 672 ? 2 : 3));
}
__global__ void nbr_kernel(int* __restrict__ nbr, int* __restrict__ ncnt)
{
    int i = blockIdx.x * blockDim.x + threadIdx.x;
    if (i >= NTOK) return;
    const int starts[4] = {0, 512, 640, 672};
    int si = scale_of(i);
    int cnt = 0;
    for (int j = 0; j < NTOK; ++j) {
        int sj = scale_of(j);
        bool a = false;
        if (si == sj)            a = (j >= i-2) && (j <= i+2);
        else if (si == sj + 1)   a = ((j - starts[sj]) >> 2) == (i - starts[si]);
        else if (sj == si + 1)   a = ((i - starts[si]) >> 2) == (j - starts[sj]);
        if (a && cnt < 16) nbr[i*16 + cnt++] = j;
    }
    ncnt[i] = cnt;
}

// ---------------- sparse masked attention ----------------
// block = (b,n) row; 4 waves, wave = head h; lane = dim d
__global__ __launch_bounds__(256) void attn_kernel(
    const float* __restrict__ Q, const float* __restrict__ K,
    const float* __restrict__ V, float* __restrict__ O,
    const int* __restrict__ nbr, const int* __restrict__ ncnt)
{
    int row = blockIdx.x;            // b*680 + n
    int n = row % NTOK;
    int b = row / NTOK;
    int h = threadIdx.x >> 6;
    int d = threadIdx.x & 63;
    float qd = Q[(size_t)row*DM + h*64 + d];
    int cnt = ncnt[n];
    float s[16];
    int jrow[16];
    #pragma unroll
    for (int jj = 0; jj < 16; ++jj) {
        float p = 0.f;
        int jr = row;
        if (jj < cnt) {
            int j = nbr[n*16 + jj];
            jr = b*NTOK + j;
            p = qd * K[(size_t)jr*DM + h*64 + d];
        }
        jrow[jj] = jr;
        #pragma unroll
        for (int o = 32; o; o >>= 1) p += __shfl_xor(p, o);
        s[jj] = (jj < cnt) ? p * 0.125f : -1e30f;
    }
    float m = s[0];
    #pragma unroll
    for (int jj = 1; jj < 16; ++jj) m = fmaxf(m, s[jj]);
    float denom = 0.f, out = 0.f;
    #pragma unroll
    for (int jj = 0; jj < 16; ++jj) {
        if (jj < cnt) {
            float w = expf(s[jj] - m);
            denom += w;
            out = fmaf(w, V[(size_t)jrow[jj]*DM + h*64 + d], out);
        }
    }
    O[(size_t)row*DM + h*64 + d] = out / denom;
}

// ---------------- generic fp32 GEMM: C[M,Nc] = A[M,K] @ W[K,Nc] + bias (opt relu) ----------------
// 64x64 tile, BK=16, 256 threads, 4x4 micro-tile
__global__ __launch_bounds__(256) void gemm_kernel(
    const float* __restrict__ A, const float* __restrict__ W,
    const float* __restrict__ bias, float* __restrict__ C,
    int M, int K, int Nc, int relu)
{
    __shared__ float As[16][64];
    __shared__ float Bs[16][64];
    int t = threadIdx.x;
    int tx = t & 15, ty = t >> 4;
    int row0 = blockIdx.x * 64, col0 = blockIdx.y * 64;
    int arow = t >> 2, ak = (t & 3) << 2;
    int brow = t >> 4, bcol = (t & 15) << 2;
    const float* Aptr = A + (size_t)(row0 + arow)*K + ak;
    const float* Wptr = W + (size_t)brow*Nc + col0 + bcol;
    float acc[4][4] = {};
    for (int kt = 0; kt < K; kt += 16) {
        float4 av = *(const float4*)(Aptr + kt);
        float4 bv = *(const float4*)(Wptr + (size_t)kt*Nc);
        __syncthreads();
        As[ak+0][arow] = av.x; As[ak+1][arow] = av.y;
        As[ak+2][arow] = av.z; As[ak+3][arow] = av.w;
        *(float4*)&Bs[brow][bcol] = bv;
        __syncthreads();
        #pragma unroll
        for (int k = 0; k < 16; ++k) {
            const float4 a = *(const float4*)&As[k][ty<<2];
            const float4 bb = *(const float4*)&Bs[k][tx<<2];
            float av4[4] = {a.x, a.y, a.z, a.w};
            float bv4[4] = {bb.x, bb.y, bb.z, bb.w};
            #pragma unroll
            for (int i = 0; i < 4; ++i)
                #pragma unroll
                for (int j = 0; j < 4; ++j)
                    acc[i][j] = fmaf(av4[i], bv4[j], acc[i][j]);
        }
    }
    #pragma unroll
    for (int i = 0; i < 4; ++i) {
        int r = row0 + ty*4 + i;
        float4 o;
        o.x = acc[i][0] + bias[col0 + tx*4 + 0];
        o.y = acc[i][1] + bias[col0 + tx*4 + 1];
        o.z = acc[i][2] + bias[col0 + tx*4 + 2];
        o.w = acc[i][3] + bias[col0 + tx*4 + 3];
        if (relu) {
            o.x = fmaxf(o.x, 0.f); o.y = fmaxf(o.y, 0.f);
            o.z = fmaxf(o.z, 0.f); o.w = fmaxf(o.w, 0.f);
        }
        *(float4*)&C[(size_t)r*Nc + col0 + tx*4] = o;
    }
}

// ---------------- final decoder projection ----------------
// out[b,o] = concat(x[b, {511,639,671,679}]) @ Wp + bp
__global__ __launch_bounds__(128) void final_kernel(
    const float* __restrict__ X, const float* __restrict__ Wp,
    const float* __restrict__ bp, float* __restrict__ out)
{
    __shared__ float rows[1024];
    int b = blockIdx.x, t = threadIdx.x;
    for (int u = t; u < 1024; u += 128) {
        int g = u >> 8;
        int id = (g == 0) ? 511 : (g == 1) ? 639 : (g == 2) ? 671 : 679;
        rows[u] = X[((size_t)(b*NTOK + id))*DM + (u & 255)];
    }
    __syncthreads();
    if (t < 96) {
        float acc = bp[t];
        #pragma unroll 8
        for (int k = 0; k < 1024; ++k) acc = fmaf(rows[k], Wp[k*96 + t], acc);
        out[b*96 + t] = acc;
    }
}

// ---------------- host launch ----------------
extern "C" void kernel_launch(void* const* d_in, const int* in_sizes, int n_in,
                              void* d_out, int out_size, void* d_ws, size_t ws_size,
                              hipStream_t stream)
{
    const float* x_enc  = (const float*)d_in[0];
    const float* x_mark = (const float*)d_in[1];
    const float* W_val  = (const float*)d_in[2];
    const float* W_time = (const float*)d_in[3];
    const float* b_time = (const float*)d_in[4];
    const float* W_down = (const float*)d_in[5];
    const float* b_down = (const float*)d_in[6];
    const float* W_conv = (const float*)d_in[7];
    const float* b_conv = (const float*)d_in[8];
    const float* bn_g   = (const float*)d_in[9];
    const float* bn_b   = (const float*)d_in[10];
    const float* W_up   = (const float*)d_in[11];
    const float* b_up   = (const float*)d_in[12];
    const float* ln_c_g = (const float*)d_in[13];
    const float* ln_c_b = (const float*)d_in[14];
    const float* Wq     = (const float*)d_in[15];
    const float* bq     = (const float*)d_in[16];
    const float* Wk     = (const float*)d_in[17];
    const float* bk     = (const float*)d_in[18];
    const float* Wv     = (const float*)d_in[19];
    const float* bv     = (const float*)d_in[20];
    const float* Wo     = (const float*)d_in[21];
    const float* bo     = (const float*)d_in[22];
    const float* ln1_g  = (const float*)d_in[23];
    const float* ln1_b  = (const float*)d_in[24];
    const float* W1f    = (const float*)d_in[25];
    const float* b1f    = (const float*)d_in[26];
    const float* W2f    = (const float*)d_in[27];
    const float* b2f    = (const float*)d_in[28];
    const float* ln2_g  = (const float*)d_in[29];
    const float* ln2_b  = (const float*)d_in[30];
    const float* Wp     = (const float*)d_in[31];
    const float* bp     = (const float*)d_in[32];

    float* ws = (float*)d_ws;
    const size_t RB = (size_t)NROWS * DM;     // 5,570,560 floats
    float* X  = ws;
    float* Qb = X  + RB;
    float* Kb = Qb + RB;
    float* Vb = Kb + RB;
    float* Ob = Vb + RB;
    float* Pb = Ob + RB;
    float* Hd = Pb + RB;                      // 21760*512
    float* Td = Hd + (size_t)NROWS * FF;      // 32*512*64
    float* Pool = Td + (size_t)B*SEQ*64;      // 32*168*64
    int*   nbr  = (int*)(Pool + (size_t)B*168*64);
    int*   ncnt = nbr + NTOK*16;

    // embedding + CSCM
    emb_kernel<<<B*SEQ, 256, 0, stream>>>(x_enc, x_mark, W_val, W_time, b_time, X);
    down_kernel<<<(B*SEQ)/4, 256, 0, stream>>>(X, W_down, b_down, Td);
    conv_kernel<<<B*128, 64, 0, stream>>>(Td, 512, 0,   Pool, 0,   128, W_conv, b_conv, bn_g, bn_b, 0);
    conv_kernel<<<B*32,  64, 0, stream>>>(Pool, 168, 0,  Pool, 128, 32,  W_conv, b_conv, bn_g, bn_b, 1);
    conv_kernel<<<B*8,   64, 0, stream>>>(Pool, 168, 128,Pool, 160, 8,   W_conv, b_conv, bn_g, bn_b, 2);
    up_kernel<<<B*168, 256, 0, stream>>>(Pool, W_up, b_up, X);
    ln_kernel<<<NROWS, 256, 0, stream>>>(X, nullptr, ln_c_g, ln_c_b);
    nbr_kernel<<<11, 64, 0, stream>>>(nbr, ncnt);

    // 2 encoder layers
    for (int l = 0; l < 2; ++l) {
        const float* wq = Wq + (size_t)l*DM*DM;  const float* bq_ = bq + l*DM;
        const float* wk = Wk + (size_t)l*DM*DM;  const float* bk_ = bk + l*DM;
        const float* wv = Wv + (size_t)l*DM*DM;  const float* bv_ = bv + l*DM;
        const float* wo = Wo + (size_t)l*DM*DM;  const float* bo_ = bo + l*DM;
        const float* w1 = W1f + (size_t)l*DM*FF; const float* b1_ = b1f + l*FF;
        const float* w2 = W2f + (size_t)l*FF*DM; const float* b2_ = b2f + l*DM;

        gemm_kernel<<<dim3(NROWS/64, DM/64), 256, 0, stream>>>(X, wq, bq_, Qb, NROWS, DM, DM, 0);
        gemm_kernel<<<dim3(NROWS/64, DM/64), 256, 0, stream>>>(X, wk, bk_, Kb, NROWS, DM, DM, 0);
        gemm_kernel<<<dim3(NROWS/64, DM/64), 256, 0, stream>>>(X, wv, bv_, Vb, NROWS, DM, DM, 0);
        attn_kernel<<<NROWS, 256, 0, stream>>>(Qb, Kb, Vb, Ob, nbr, ncnt);
        gemm_kernel<<<dim3(NROWS/64, DM/64), 256, 0, stream>>>(Ob, wo, bo_, Pb, NROWS, DM, DM, 0);
        ln_kernel<<<NROWS, 256, 0, stream>>>(X, Pb, ln1_g + l*DM, ln1_b + l*DM);
        gemm_kernel<<<dim3(NROWS/64, FF/64), 256, 0, stream>>>(X, w1, b1_, Hd, NROWS, DM, FF, 1);
        gemm_kernel<<<dim3(NROWS/64, DM/64), 256, 0, stream>>>(Hd, w2, b2_, Pb, NROWS, FF, DM, 0);
        ln_kernel<<<NROWS, 256, 0, stream>>>(X, Pb, ln2_g + l*DM, ln2_b + l*DM);
    }

    final_kernel<<<B, 128, 0, stream>>>(X, Wp, bp, (float*)d_out);
}

// Round 2
// 953.911 us; speedup vs baseline: 1.2917x; 1.2917x over previous
//
#include <hip/hip_runtime.h>
#include <hip/hip_bf16.h>
#include <math.h>

// ---------------- constants ----------------
#define B 32
#define SEQ 512
#define NTOK 680           // 512+128+32+8
#define DM 256
#define HEADS 4
#define DK 64
#define FF 512
#define NROWS (B*NTOK)     // 21760

using bf16x8 = __attribute__((ext_vector_type(8))) short;
using f32x4  = __attribute__((ext_vector_type(4))) float;
typedef __hip_bfloat16 bf16;

// ---------------- embedding ----------------
__global__ __launch_bounds__(256) void emb_kernel(
    const float* __restrict__ x_enc, const float* __restrict__ x_mark,
    const float* __restrict__ W_val, const float* __restrict__ W_time,
    const float* __restrict__ b_time, float* __restrict__ X)
{
    int bs = blockIdx.x;
    int b = bs >> 9, s = bs & 511;
    int d = threadIdx.x;
    int sm1 = (s + 511) & 511, sp1 = (s + 1) & 511;
    float x0 = x_enc[b*512 + sm1];
    float x1 = x_enc[b*512 + s];
    float x2 = x_enc[b*512 + sp1];
    float val = x0 * W_val[d*3+0] + x1 * W_val[d*3+1] + x2 * W_val[d*3+2];
    const float* mk = &x_mark[(size_t)bs*4];
    float tm = mk[0]*W_time[d] + mk[1]*W_time[256+d] + mk[2]*W_time[512+d] + mk[3]*W_time[768+d];
    int i2 = d & ~1;
    float div = expf((float)i2 * (-9.210340371976184f / 256.0f));
    float ang = (float)s * div;
    float pe = (d & 1) ? cosf(ang) : sinf(ang);
    X[((size_t)(b*NTOK + s))*DM + d] = val + tm + b_time[d] + pe;
}

// ---------------- CSCM down-projection ----------------
__global__ __launch_bounds__(256) void down_kernel(
    const float* __restrict__ X, const float* __restrict__ W_down,
    const float* __restrict__ b_down, float* __restrict__ Td)
{
    __shared__ float rows[4][256];
    int g = blockIdx.x;
    int t = threadIdx.x;
    int r = t >> 6, c = t & 63;
    int bs = g*4 + r;
    int xrow = (bs >> 9)*NTOK + (bs & 511);
    for (int u = c; u < 256; u += 64) rows[r][u] = X[(size_t)xrow*DM + u];
    __syncthreads();
    float acc = b_down[c];
    #pragma unroll 8
    for (int k = 0; k < 256; ++k) acc = fmaf(rows[r][k], W_down[k*64 + c], acc);
    Td[(size_t)bs*64 + c] = acc;
}

// ---------------- CSCM strided conv + BN affine + ELU ----------------
__global__ __launch_bounds__(64) void conv_kernel(
    const float* __restrict__ in, int inRPB, int inOff,
    float* __restrict__ Pool, int outOff, int Lout,
    const float* __restrict__ W_conv, const float* __restrict__ b_conv,
    const float* __restrict__ bn_g, const float* __restrict__ bn_b, int sc)
{
    __shared__ float lds[256];
    int blk = blockIdx.x;
    int b = blk / Lout, p = blk % Lout;
    int t = threadIdx.x;
    for (int u = t; u < 256; u += 64)
        lds[u] = in[((size_t)(b*inRPB + inOff + p*4 + (u >> 6)))*64 + (u & 63)];
    __syncthreads();
    float acc = b_conv[sc*64 + t];
    const float* w = &W_conv[(size_t)(sc*64 + t)*256];
    #pragma unroll 4
    for (int ci = 0; ci < 64; ++ci) {
        #pragma unroll
        for (int tap = 0; tap < 4; ++tap)
            acc = fmaf(lds[tap*64 + ci], w[ci*4 + tap], acc);
    }
    float v = acc * bn_g[sc*64 + t] + bn_b[sc*64 + t];
    v = v > 0.f ? v : expm1f(v);
    Pool[((size_t)(b*168 + outOff + p))*64 + t] = v;
}

// ---------------- CSCM up-projection ----------------
__global__ __launch_bounds__(256) void up_kernel(
    const float* __restrict__ Pool, const float* __restrict__ W_up,
    const float* __restrict__ b_up, float* __restrict__ X)
{
    __shared__ float row[64];
    int blk = blockIdx.x;
    int b = blk / 168, p = blk % 168;
    int d = threadIdx.x;
    if (d < 64) row[d] = Pool[(size_t)blk*64 + d];
    __syncthreads();
    float acc = b_up[d];
    #pragma unroll 8
    for (int k = 0; k < 64; ++k) acc = fmaf(row[k], W_up[k*256 + d], acc);
    X[((size_t)(b*NTOK + 512 + p))*DM + d] = acc;
}

// ---------------- LayerNorm (optional residual add), writes fp32 + bf16 ----------------
__global__ __launch_bounds__(256) void ln_kernel(
    float* __restrict__ X, const float* __restrict__ add,
    const float* __restrict__ g, const float* __restrict__ bta,
    bf16* __restrict__ Xh)
{
    __shared__ float sm[4];
    int r = blockIdx.x, t = threadIdx.x;
    float v = X[(size_t)r*DM + t];
    if (add) v += add[(size_t)r*DM + t];
    float s = v;
    #pragma unroll
    for (int o = 32; o; o >>= 1) s += __shfl_xor(s, o);
    if ((t & 63) == 0) sm[t >> 6] = s;
    __syncthreads();
    float mean = (sm[0]+sm[1]+sm[2]+sm[3]) * (1.0f/256.0f);
    __syncthreads();
    float dv = v - mean;
    float q = dv*dv;
    #pragma unroll
    for (int o = 32; o; o >>= 1) q += __shfl_xor(q, o);
    if ((t & 63) == 0) sm[t >> 6] = q;
    __syncthreads();
    float var = (sm[0]+sm[1]+sm[2]+sm[3]) * (1.0f/256.0f);
    float out = dv * rsqrtf(var + 1e-5f) * g[t] + bta[t];
    X[(size_t)r*DM + t] = out;
    Xh[(size_t)r*DM + t] = __float2bfloat16(out);
}

// ---------------- neighbor lists ----------------
__device__ __forceinline__ int scale_of(int p) {
    return p < 512 ? 0 : (p < 640 ? 1 : (p < 672 ? 2 : 3));
}
__global__ void nbr_kernel(int* __restrict__ nbr, int* __restrict__ ncnt)
{
    int i = blockIdx.x * blockDim.x + threadIdx.x;
    if (i >= NTOK) return;
    const int starts[4] = {0, 512, 640, 672};
    int si = scale_of(i);
    int cnt = 0;
    for (int j = 0; j < NTOK; ++j) {
        int sj = scale_of(j);
        bool a = false;
        if (si == sj)            a = (j >= i-2) && (j <= i+2);
        else if (si == sj + 1)   a = ((j - starts[sj]) >> 2) == (i - starts[si]);
        else if (sj == si + 1)   a = ((i - starts[si]) >> 2) == (j - starts[sj]);
        if (a && cnt < 16) nbr[i*16 + cnt++] = j;
    }
    ncnt[i] = cnt;
}

// ---------------- sparse masked attention (bf16 QKV in, bf16 O out) ----------------
__global__ __launch_bounds__(256) void attn_kernel(
    const bf16* __restrict__ Q, const bf16* __restrict__ K,
    const bf16* __restrict__ V, bf16* __restrict__ O,
    const int* __restrict__ nbr, const int* __restrict__ ncnt)
{
    int row = blockIdx.x;            // b*680 + n
    int n = row % NTOK;
    int b = row / NTOK;
    int h = threadIdx.x >> 6;
    int d = threadIdx.x & 63;
    float qd = __bfloat162float(Q[(size_t)row*DM + h*64 + d]);
    int cnt = ncnt[n];
    float s[16];
    int jrow[16];
    #pragma unroll
    for (int jj = 0; jj < 16; ++jj) {
        float p = 0.f;
        int jr = row;
        if (jj < cnt) {
            int j = nbr[n*16 + jj];
            jr = b*NTOK + j;
            p = qd * __bfloat162float(K[(size_t)jr*DM + h*64 + d]);
        }
        jrow[jj] = jr;
        #pragma unroll
        for (int o = 32; o; o >>= 1) p += __shfl_xor(p, o);
        s[jj] = (jj < cnt) ? p * 0.125f : -1e30f;
    }
    float m = s[0];
    #pragma unroll
    for (int jj = 1; jj < 16; ++jj) m = fmaxf(m, s[jj]);
    float denom = 0.f, out = 0.f;
    #pragma unroll
    for (int jj = 0; jj < 16; ++jj) {
        if (jj < cnt) {
            float w = expf(s[jj] - m);
            denom += w;
            out = fmaf(w, __bfloat162float(V[(size_t)jrow[jj]*DM + h*64 + d]), out);
        }
    }
    O[(size_t)row*DM + h*64 + d] = __float2bfloat16(out / denom);
}

// ---------------- weight transpose + bf16 convert ----------------
struct WDesc { const float* src; bf16* dst; int n_total; int kshift; int N; };
struct WTable { WDesc d[12]; };
__global__ __launch_bounds__(256) void wconv_kernel(WTable tbl)
{
    WDesc ds = tbl.d[blockIdx.y];
    int e = blockIdx.x * 256 + threadIdx.x;
    if (e >= ds.n_total) return;
    int n = e >> ds.kshift;
    int k = e & ((1 << ds.kshift) - 1);
    ds.dst[e] = __float2bfloat16(ds.src[(size_t)k * ds.N + n]);
}

// ---------------- MFMA bf16 GEMM ----------------
// tile 128(M) x 64(N), BK=64, 256 thr (4 waves as 2Mx2N), 16x16x32 bf16 MFMA
// W is pre-transposed: [Nc][K] bf16. z selects among 3 weight/bias/out sets.
template<int KD, bool RELU, bool OUTBF>
__global__ __launch_bounds__(256) void mfma_gemm(
    const bf16* __restrict__ A,
    const bf16* __restrict__ Wt0, const bf16* __restrict__ Wt1, const bf16* __restrict__ Wt2,
    const float* __restrict__ b0, const float* __restrict__ b1, const float* __restrict__ b2,
    void* __restrict__ O0, void* __restrict__ O1, void* __restrict__ O2,
    int Nc)
{
    __shared__ uint4 AsU[128*8];   // [row][granule^swz], 16KB
    __shared__ uint4 BsU[64*8];    // 8KB
    int t = threadIdx.x;
    int lane = t & 63, wid = t >> 6;
    int wm = wid >> 1, wn = wid & 1;
    int row0 = blockIdx.x * 128;
    int n0 = blockIdx.y * 64;
    int z = blockIdx.z;
    const bf16* W = (z == 0) ? Wt0 : (z == 1) ? Wt1 : Wt2;
    const float* bias = (z == 0) ? b0 : (z == 1) ? b1 : b2;
    void* Op = (z == 0) ? O0 : (z == 1) ? O1 : O2;

    f32x4 acc[4][2];
    #pragma unroll
    for (int i = 0; i < 4; ++i)
        #pragma unroll
        for (int j = 0; j < 2; ++j)
            #pragma unroll
            for (int r = 0; r < 4; ++r) acc[i][j][r] = 0.f;

    uint4 pa[4], pb[2];
    #pragma unroll
    for (int i = 0; i < 4; ++i) {
        int g = t + i*256, r = g >> 3, c = g & 7;
        pa[i] = *reinterpret_cast<const uint4*>(A + (size_t)(row0 + r)*KD + c*8);
    }
    #pragma unroll
    for (int i = 0; i < 2; ++i) {
        int g = t + i*256, r = g >> 3, c = g & 7;
        pb[i] = *reinterpret_cast<const uint4*>(W + (size_t)(n0 + r)*KD + c*8);
    }

    const bf16x8* Asv = reinterpret_cast<const bf16x8*>(AsU);
    const bf16x8* Bsv = reinterpret_cast<const bf16x8*>(BsU);

    #pragma unroll
    for (int kt = 0; kt < KD; kt += 64) {
        __syncthreads();
        #pragma unroll
        for (int i = 0; i < 4; ++i) {
            int g = t + i*256, r = g >> 3, c = g & 7;
            AsU[r*8 + (c ^ (r & 7))] = pa[i];
        }
        #pragma unroll
        for (int i = 0; i < 2; ++i) {
            int g = t + i*256, r = g >> 3, c = g & 7;
            BsU[r*8 + (c ^ (r & 7))] = pb[i];
        }
        __syncthreads();
        if (kt + 64 < KD) {
            #pragma unroll
            for (int i = 0; i < 4; ++i) {
                int g = t + i*256, r = g >> 3, c = g & 7;
                pa[i] = *reinterpret_cast<const uint4*>(A + (size_t)(row0 + r)*KD + (kt + 64) + c*8);
            }
            #pragma unroll
            for (int i = 0; i < 2; ++i) {
                int g = t + i*256, r = g >> 3, c = g & 7;
                pb[i] = *reinterpret_cast<const uint4*>(W + (size_t)(n0 + r)*KD + (kt + 64) + c*8);
            }
        }
        #pragma unroll
        for (int ks = 0; ks < 2; ++ks) {
            int cg = ks*4 + (lane >> 4);
            bf16x8 af[4], bfr[2];
            #pragma unroll
            for (int m = 0; m < 4; ++m) {
                int ar = wm*64 + m*16 + (lane & 15);
                af[m] = Asv[ar*8 + (cg ^ (ar & 7))];
            }
            #pragma unroll
            for (int n = 0; n < 2; ++n) {
                int br = wn*32 + n*16 + (lane & 15);
                bfr[n] = Bsv[br*8 + (cg ^ (br & 7))];
            }
            #pragma unroll
            for (int m = 0; m < 4; ++m)
                #pragma unroll
                for (int n = 0; n < 2; ++n)
                    acc[m][n] = __builtin_amdgcn_mfma_f32_16x16x32_bf16(af[m], bfr[n], acc[m][n], 0, 0, 0);
        }
    }

    // epilogue: C[row][col], row=(lane>>4)*4+r within 16x16 frag, col=lane&15
    #pragma unroll
    for (int m = 0; m < 4; ++m) {
        #pragma unroll
        for (int n = 0; n < 2; ++n) {
            int col = n0 + wn*32 + n*16 + (lane & 15);
            float bcol = bias[col];
            #pragma unroll
            for (int r = 0; r < 4; ++r) {
                int rowi = row0 + wm*64 + m*16 + (lane >> 4)*4 + r;
                float v = acc[m][n][r] + bcol;
                if (RELU) v = fmaxf(v, 0.f);
                if (OUTBF) ((bf16*)Op)[(size_t)rowi*Nc + col] = __float2bfloat16(v);
                else       ((float*)Op)[(size_t)rowi*Nc + col] = v;
            }
        }
    }
}

// ---------------- final decoder projection ----------------
__global__ __launch_bounds__(128) void final_kernel(
    const float* __restrict__ X, const float* __restrict__ Wp,
    const float* __restrict__ bp, float* __restrict__ out)
{
    __shared__ float rows[1024];
    int b = blockIdx.x, t = threadIdx.x;
    for (int u = t; u < 1024; u += 128) {
        int g = u >> 8;
        int id = (g == 0) ? 511 : (g == 1) ? 639 : (g == 2) ? 671 : 679;
        rows[u] = X[((size_t)(b*NTOK + id))*DM + (u & 255)];
    }
    __syncthreads();
    if (t < 96) {
        float acc = bp[t];
        #pragma unroll 8
        for (int k = 0; k < 1024; ++k) acc = fmaf(rows[k], Wp[k*96 + t], acc);
        out[b*96 + t] = acc;
    }
}

// ---------------- host launch ----------------
extern "C" void kernel_launch(void* const* d_in, const int* in_sizes, int n_in,
                              void* d_out, int out_size, void* d_ws, size_t ws_size,
                              hipStream_t stream)
{
    const float* x_enc  = (const float*)d_in[0];
    const float* x_mark = (const float*)d_in[1];
    const float* W_val  = (const float*)d_in[2];
    const float* W_time = (const float*)d_in[3];
    const float* b_time = (const float*)d_in[4];
    const float* W_down = (const float*)d_in[5];
    const float* b_down = (const float*)d_in[6];
    const float* W_conv = (const float*)d_in[7];
    const float* b_conv = (const float*)d_in[8];
    const float* bn_g   = (const float*)d_in[9];
    const float* bn_b   = (const float*)d_in[10];
    const float* W_up   = (const float*)d_in[11];
    const float* b_up   = (const float*)d_in[12];
    const float* ln_c_g = (const float*)d_in[13];
    const float* ln_c_b = (const float*)d_in[14];
    const float* Wq     = (const float*)d_in[15];
    const float* bq     = (const float*)d_in[16];
    const float* Wk     = (const float*)d_in[17];
    const float* bk     = (const float*)d_in[18];
    const float* Wv     = (const float*)d_in[19];
    const float* bv     = (const float*)d_in[20];
    const float* Wo     = (const float*)d_in[21];
    const float* bo     = (const float*)d_in[22];
    const float* ln1_g  = (const float*)d_in[23];
    const float* ln1_b  = (const float*)d_in[24];
    const float* W1f    = (const float*)d_in[25];
    const float* b1f    = (const float*)d_in[26];
    const float* W2f    = (const float*)d_in[27];
    const float* b2f    = (const float*)d_in[28];
    const float* ln2_g  = (const float*)d_in[29];
    const float* ln2_b  = (const float*)d_in[30];
    const float* Wp     = (const float*)d_in[31];
    const float* bp     = (const float*)d_in[32];

    const size_t RB = (size_t)NROWS * DM;     // 5,570,560
    float* ws = (float*)d_ws;
    float* X    = ws;                          // fp32
    float* Pb   = X + RB;
    float* Td   = Pb + RB;                     // 32*512*64
    float* Pool = Td + (size_t)B*SEQ*64;       // 32*168*64
    bf16* bws   = (bf16*)(Pool + (size_t)B*168*64);
    bf16* Xh   = bws;
    bf16* Qh   = Xh  + RB;
    bf16* Kh   = Qh  + RB;
    bf16* Vh   = Kh  + RB;
    bf16* Obh  = Vh  + RB;
    bf16* Hdh  = Obh + RB;                     // NROWS*512
    bf16* WqT  = Hdh + (size_t)NROWS*FF;       // per layer 65536
    bf16* WkT  = WqT + 2*65536;
    bf16* WvT  = WkT + 2*65536;
    bf16* WoT  = WvT + 2*65536;
    bf16* W1T  = WoT + 2*65536;                // per layer 131072 ([512][256])
    bf16* W2T  = W1T + 2*131072;               // per layer 131072 ([256][512])
    int*  nbr  = (int*)(W2T + 2*131072);
    int*  ncnt = nbr + NTOK*16;

    // weight transpose+convert (all 12 weights, one dispatch)
    WTable tbl;
    for (int l = 0; l < 2; ++l) {
        tbl.d[l*6+0] = { Wq  + (size_t)l*65536,  WqT + (size_t)l*65536,  65536, 8, 256 };
        tbl.d[l*6+1] = { Wk  + (size_t)l*65536,  WkT + (size_t)l*65536,  65536, 8, 256 };
        tbl.d[l*6+2] = { Wv  + (size_t)l*65536,  WvT + (size_t)l*65536,  65536, 8, 256 };
        tbl.d[l*6+3] = { Wo  + (size_t)l*65536,  WoT + (size_t)l*65536,  65536, 8, 256 };
        tbl.d[l*6+4] = { W1f + (size_t)l*131072, W1T + (size_t)l*131072, 131072, 8, 512 }; // dst [512][256]
        tbl.d[l*6+5] = { W2f + (size_t)l*131072, W2T + (size_t)l*131072, 131072, 9, 256 }; // dst [256][512]
    }
    wconv_kernel<<<dim3(512, 12), 256, 0, stream>>>(tbl);

    // embedding + CSCM
    emb_kernel<<<B*SEQ, 256, 0, stream>>>(x_enc, x_mark, W_val, W_time, b_time, X);
    down_kernel<<<(B*SEQ)/4, 256, 0, stream>>>(X, W_down, b_down, Td);
    conv_kernel<<<B*128, 64, 0, stream>>>(Td, 512, 0,   Pool, 0,   128, W_conv, b_conv, bn_g, bn_b, 0);
    conv_kernel<<<B*32,  64, 0, stream>>>(Pool, 168, 0,  Pool, 128, 32,  W_conv, b_conv, bn_g, bn_b, 1);
    conv_kernel<<<B*8,   64, 0, stream>>>(Pool, 168, 128,Pool, 160, 8,   W_conv, b_conv, bn_g, bn_b, 2);
    up_kernel<<<B*168, 256, 0, stream>>>(Pool, W_up, b_up, X);
    ln_kernel<<<NROWS, 256, 0, stream>>>(X, nullptr, ln_c_g, ln_c_b, Xh);
    nbr_kernel<<<11, 64, 0, stream>>>(nbr, ncnt);

    // 2 encoder layers
    for (int l = 0; l < 2; ++l) {
        const bf16* wqt = WqT + (size_t)l*65536;
        const bf16* wkt = WkT + (size_t)l*65536;
        const bf16* wvt = WvT + (size_t)l*65536;
        const bf16* wot = WoT + (size_t)l*65536;
        const bf16* w1t = W1T + (size_t)l*131072;
        const bf16* w2t = W2T + (size_t)l*131072;
        const float* bq_ = bq + l*DM; const float* bk_ = bk + l*DM;
        const float* bv_ = bv + l*DM; const float* bo_ = bo + l*DM;
        const float* b1_ = b1f + l*FF; const float* b2_ = b2f + l*DM;

        // fused QKV: z selects weight/bias/output
        mfma_gemm<256,false,true><<<dim3(NROWS/128, 4, 3), 256, 0, stream>>>(
            Xh, wqt, wkt, wvt, bq_, bk_, bv_, Qh, Kh, Vh, 256);
        attn_kernel<<<NROWS, 256, 0, stream>>>(Qh, Kh, Vh, Obh, nbr, ncnt);
        mfma_gemm<256,false,false><<<dim3(NROWS/128, 4, 1), 256, 0, stream>>>(
            Obh, wot, wot, wot, bo_, bo_, bo_, Pb, Pb, Pb, 256);
        ln_kernel<<<NROWS, 256, 0, stream>>>(X, Pb, ln1_g + l*DM, ln1_b + l*DM, Xh);
        mfma_gemm<256,true,true><<<dim3(NROWS/128, 8, 1), 256, 0, stream>>>(
            Xh, w1t, w1t, w1t, b1_, b1_, b1_, Hdh, Hdh, Hdh, 512);
        mfma_gemm<512,false,false><<<dim3(NROWS/128, 4, 1), 256, 0, stream>>>(
            Hdh, w2t, w2t, w2t, b2_, b2_, b2_, Pb, Pb, Pb, 256);
        ln_kernel<<<NROWS, 256, 0, stream>>>(X, Pb, ln2_g + l*DM, ln2_b + l*DM, Xh);
    }

    final_kernel<<<B, 128, 0, stream>>>(X, Wp, bp, (float*)d_out);
}

// Round 3
// 732.364 us; speedup vs baseline: 1.6825x; 1.3025x over previous
//
#include <hip/hip_runtime.h>
#include <hip/hip_bf16.h>
#include <math.h>

// ---------------- constants ----------------
#define B 32
#define SEQ 512
#define NTOK 680           // 512+128+32+8
#define DM 256
#define FF 512
#define NROWS (B*NTOK)     // 21760

using bf16x8 = __attribute__((ext_vector_type(8))) short;
using f32x4  = __attribute__((ext_vector_type(4))) float;
typedef __hip_bfloat16 bf16;

__device__ __forceinline__ unsigned short f2bf(float f) {
    union { float f; unsigned u; } x; x.f = f;
    unsigned r = (x.u + 0x7fffu + ((x.u >> 16) & 1u)) >> 16;
    return (unsigned short)r;
}
__device__ __forceinline__ float bfu2f(unsigned short u) {
    union { unsigned u; float f; } x; x.u = ((unsigned)u) << 16;
    return x.f;
}
__device__ __forceinline__ void dotu(unsigned a, unsigned b, float& s) {
    union { unsigned u; float f; } al, ah, bl, bh;
    al.u = a << 16; ah.u = a & 0xffff0000u;
    bl.u = b << 16; bh.u = b & 0xffff0000u;
    s = fmaf(al.f, bl.f, s);
    s = fmaf(ah.f, bh.f, s);
}

// ---------------- embedding ----------------
__global__ __launch_bounds__(256) void emb_kernel(
    const float* __restrict__ x_enc, const float* __restrict__ x_mark,
    const float* __restrict__ W_val, const float* __restrict__ W_time,
    const float* __restrict__ b_time, float* __restrict__ X)
{
    int bs = blockIdx.x;
    int b = bs >> 9, s = bs & 511;
    int d = threadIdx.x;
    int sm1 = (s + 511) & 511, sp1 = (s + 1) & 511;
    float x0 = x_enc[b*512 + sm1];
    float x1 = x_enc[b*512 + s];
    float x2 = x_enc[b*512 + sp1];
    float val = x0 * W_val[d*3+0] + x1 * W_val[d*3+1] + x2 * W_val[d*3+2];
    const float* mk = &x_mark[(size_t)bs*4];
    float tm = mk[0]*W_time[d] + mk[1]*W_time[256+d] + mk[2]*W_time[512+d] + mk[3]*W_time[768+d];
    int i2 = d & ~1;
    float div = expf((float)i2 * (-9.210340371976184f / 256.0f));
    float ang = (float)s * div;
    float pe = (d & 1) ? cosf(ang) : sinf(ang);
    X[((size_t)(b*NTOK + s))*DM + d] = val + tm + b_time[d] + pe;
}

// ---------------- CSCM down-projection ----------------
__global__ __launch_bounds__(256) void down_kernel(
    const float* __restrict__ X, const float* __restrict__ W_down,
    const float* __restrict__ b_down, float* __restrict__ Td)
{
    __shared__ float rows[4][256];
    int g = blockIdx.x;
    int t = threadIdx.x;
    int r = t >> 6, c = t & 63;
    int bs = g*4 + r;
    int xrow = (bs >> 9)*NTOK + (bs & 511);
    for (int u = c; u < 256; u += 64) rows[r][u] = X[(size_t)xrow*DM + u];
    __syncthreads();
    float acc = b_down[c];
    #pragma unroll 8
    for (int k = 0; k < 256; ++k) acc = fmaf(rows[r][k], W_down[k*64 + c], acc);
    Td[(size_t)bs*64 + c] = acc;
}

// ---------------- CSCM strided conv + BN affine + ELU ----------------
__global__ __launch_bounds__(64) void conv_kernel(
    const float* __restrict__ in, int inRPB, int inOff,
    float* __restrict__ Pool, int outOff, int Lout,
    const float* __restrict__ W_conv, const float* __restrict__ b_conv,
    const float* __restrict__ bn_g, const float* __restrict__ bn_b, int sc)
{
    __shared__ float lds[256];
    int blk = blockIdx.x;
    int b = blk / Lout, p = blk % Lout;
    int t = threadIdx.x;
    for (int u = t; u < 256; u += 64)
        lds[u] = in[((size_t)(b*inRPB + inOff + p*4 + (u >> 6)))*64 + (u & 63)];
    __syncthreads();
    float acc = b_conv[sc*64 + t];
    const float* w = &W_conv[(size_t)(sc*64 + t)*256];
    #pragma unroll 4
    for (int ci = 0; ci < 64; ++ci) {
        #pragma unroll
        for (int tap = 0; tap < 4; ++tap)
            acc = fmaf(lds[tap*64 + ci], w[ci*4 + tap], acc);
    }
    float v = acc * bn_g[sc*64 + t] + bn_b[sc*64 + t];
    v = v > 0.f ? v : expm1f(v);
    Pool[((size_t)(b*168 + outOff + p))*64 + t] = v;
}

// ---------------- CSCM up-projection ----------------
__global__ __launch_bounds__(256) void up_kernel(
    const float* __restrict__ Pool, const float* __restrict__ W_up,
    const float* __restrict__ b_up, float* __restrict__ X)
{
    __shared__ float row[64];
    int blk = blockIdx.x;
    int b = blk / 168, p = blk % 168;
    int d = threadIdx.x;
    if (d < 64) row[d] = Pool[(size_t)blk*64 + d];
    __syncthreads();
    float acc = b_up[d];
    #pragma unroll 8
    for (int k = 0; k < 64; ++k) acc = fmaf(row[k], W_up[k*256 + d], acc);
    X[((size_t)(b*NTOK + 512 + p))*DM + d] = acc;
}

// ---------------- LayerNorm: one wave per row, float4 lanes ----------------
__global__ __launch_bounds__(256) void ln_kernel(
    float* __restrict__ X, const float* __restrict__ add,
    const float* __restrict__ g, const float* __restrict__ bta,
    bf16* __restrict__ Xh)
{
    int r = blockIdx.x*4 + (threadIdx.x >> 6);
    int lane = threadIdx.x & 63;
    float4 v = ((const float4*)(X + (size_t)r*DM))[lane];
    if (add) {
        float4 a = ((const float4*)(add + (size_t)r*DM))[lane];
        v.x += a.x; v.y += a.y; v.z += a.z; v.w += a.w;
    }
    float s = v.x + v.y + v.z + v.w;
    #pragma unroll
    for (int o = 32; o; o >>= 1) s += __shfl_xor(s, o);
    float mean = s * (1.0f/256.0f);
    float dx = v.x-mean, dy = v.y-mean, dz = v.z-mean, dw = v.w-mean;
    float q = dx*dx + dy*dy + dz*dz + dw*dw;
    #pragma unroll
    for (int o = 32; o; o >>= 1) q += __shfl_xor(q, o);
    float inv = rsqrtf(q*(1.0f/256.0f) + 1e-5f);
    float4 gg = ((const float4*)g)[lane];
    float4 bb = ((const float4*)bta)[lane];
    float4 o4;
    o4.x = dx*inv*gg.x + bb.x;
    o4.y = dy*inv*gg.y + bb.y;
    o4.z = dz*inv*gg.z + bb.z;
    o4.w = dw*inv*gg.w + bb.w;
    ((float4*)(X + (size_t)r*DM))[lane] = o4;
    unsigned u0 = (unsigned)f2bf(o4.x) | ((unsigned)f2bf(o4.y) << 16);
    unsigned u1 = (unsigned)f2bf(o4.z) | ((unsigned)f2bf(o4.w) << 16);
    ((uint2*)(Xh + (size_t)r*DM))[lane] = make_uint2(u0, u1);
}

// ---------------- neighbor lists ----------------
__device__ __forceinline__ int scale_of(int p) {
    return p < 512 ? 0 : (p < 640 ? 1 : (p < 672 ? 2 : 3));
}
__global__ void nbr_kernel(int* __restrict__ nbr, int* __restrict__ ncnt)
{
    int i = blockIdx.x * blockDim.x + threadIdx.x;
    if (i >= NTOK) return;
    const int starts[4] = {0, 512, 640, 672};
    int si = scale_of(i);
    int cnt = 0;
    for (int j = 0; j < NTOK; ++j) {
        int sj = scale_of(j);
        bool a = false;
        if (si == sj)            a = (j >= i-2) && (j <= i+2);
        else if (si == sj + 1)   a = ((j - starts[sj]) >> 2) == (i - starts[si]);
        else if (sj == si + 1)   a = ((i - starts[si]) >> 2) == (j - starts[sj]);
        if (a && cnt < 16) nbr[i*16 + cnt++] = j;
    }
    ncnt[i] = cnt;
}

// ---------------- sparse masked attention, wave-parallel ----------------
// block = one (b,n) row (XCD-swizzled); wave = head. Phase 1: lane=(j,g)
// computes s_j over 16 dims, 2-shfl group reduce; phase 2: butterfly softmax
// over j-groups; phase 3: lane=d PV with LDS-broadcast weights.
__global__ __launch_bounds__(256) void attn_kernel(
    const bf16* __restrict__ Q, const bf16* __restrict__ K,
    const bf16* __restrict__ V, bf16* __restrict__ O,
    const int* __restrict__ nbr, const int* __restrict__ ncnt)
{
    __shared__ float wsm[4][16];
    __shared__ int   jsm[4][16];
    int flat = blockIdx.x;
    int row = (flat & 7) * (NROWS/8) + (flat >> 3);   // XCD-contiguous rows
    int n = row % NTOK, b = row / NTOK;
    int h = threadIdx.x >> 6;
    int lane = threadIdx.x & 63;
    int j = lane >> 2, g = lane & 3;
    int cnt = ncnt[n];
    int nj = (j < cnt) ? nbr[n*16 + j] : n;
    int jr = b*NTOK + nj;

    const uint4* qp = (const uint4*)(Q + (size_t)row*DM + h*64 + g*16);
    const uint4* kp = (const uint4*)(K + (size_t)jr*DM + h*64 + g*16);
    uint4 qa = qp[0], qb = qp[1];
    uint4 ka = kp[0], kb = kp[1];
    float s = 0.f;
    dotu(qa.x, ka.x, s); dotu(qa.y, ka.y, s); dotu(qa.z, ka.z, s); dotu(qa.w, ka.w, s);
    dotu(qb.x, kb.x, s); dotu(qb.y, kb.y, s); dotu(qb.z, kb.z, s); dotu(qb.w, kb.w, s);
    s += __shfl_xor(s, 1);
    s += __shfl_xor(s, 2);           // full dot in every lane of group j
    s *= 0.125f;
    if (j >= cnt) s = -1e30f;
    float m = s;
    #pragma unroll
    for (int o = 4; o < 64; o <<= 1) m = fmaxf(m, __shfl_xor(m, o));
    float w = (j < cnt) ? expf(s - m) : 0.f;
    float den = w;
    #pragma unroll
    for (int o = 4; o < 64; o <<= 1) den += __shfl_xor(den, o);
    if (g == 0) { wsm[h][j] = w / den; jsm[h][j] = jr; }
    __syncthreads();

    float acc = 0.f;
    const unsigned short* Vu = (const unsigned short*)V;
    for (int jj = 0; jj < cnt; ++jj) {
        float wv = wsm[h][jj];
        int rr = jsm[h][jj];
        acc = fmaf(wv, bfu2f(Vu[(size_t)rr*DM + h*64 + lane]), acc);
    }
    ((unsigned short*)O)[(size_t)row*DM + h*64 + lane] = f2bf(acc);
}

// ---------------- weight transpose + bf16 convert ----------------
struct WDesc { const float* src; bf16* dst; int n_total; int kshift; int N; };
struct WTable { WDesc d[12]; };
__global__ __launch_bounds__(256) void wconv_kernel(WTable tbl)
{
    WDesc ds = tbl.d[blockIdx.y];
    int e = blockIdx.x * 256 + threadIdx.x;
    if (e >= ds.n_total) return;
    int n = e >> ds.kshift;
    int k = e & ((1 << ds.kshift) - 1);
    ds.dst[e] = __float2bfloat16(ds.src[(size_t)k * ds.N + n]);
}

// ---------------- MFMA bf16 GEMM ----------------
// tile 128(M) x 64(N), BK=64, 4 waves (2Mx2N), 16x16x32 bf16 MFMA.
// Flat grid with XCD-aware swizzle: all NY*NZ blocks of one A-tile land on
// one XCD (L2 A reuse). LDS-staged epilogue for coalesced stores.
template<int KD, int NY, int NZ, bool RELU, bool OUTBF>
__global__ __launch_bounds__(256) void mfma_gemm(
    const bf16* __restrict__ A,
    const bf16* __restrict__ Wt0, const bf16* __restrict__ Wt1, const bf16* __restrict__ Wt2,
    const float* __restrict__ b0, const float* __restrict__ b1, const float* __restrict__ b2,
    void* __restrict__ O0, void* __restrict__ O1, void* __restrict__ O2,
    int Nc)
{
    __shared__ __align__(16) char smem[34816];   // staging 24KB | ctile 128*68*4
    uint4* AsU = (uint4*)smem;
    uint4* BsU = (uint4*)(smem + 16384);
    const bf16x8* Asv = (const bf16x8*)smem;
    const bf16x8* Bsv = (const bf16x8*)(smem + 16384);
    float* ctile = (float*)smem;

    int t = threadIdx.x;
    int lane = t & 63, wid = t >> 6;
    int wm = wid >> 1, wn = wid & 1;
    int nwg = gridDim.x;                          // always % 8 == 0 here
    int wg = (blockIdx.x & 7) * (nwg >> 3) + (blockIdx.x >> 3);
    int xt = wg / (NY*NZ);
    int yz = wg % (NY*NZ);
    int y = yz / NZ, z = yz % NZ;
    int row0 = xt * 128;
    int n0 = y * 64;
    const bf16* W = (z == 0) ? Wt0 : (z == 1) ? Wt1 : Wt2;
    const float* bias = (z == 0) ? b0 : (z == 1) ? b1 : b2;
    void* Op = (z == 0) ? O0 : (z == 1) ? O1 : O2;

    f32x4 acc[4][2];
    #pragma unroll
    for (int i = 0; i < 4; ++i)
        #pragma unroll
        for (int jn = 0; jn < 2; ++jn)
            #pragma unroll
            for (int r = 0; r < 4; ++r) acc[i][jn][r] = 0.f;

    uint4 pa[4], pb[2];
    #pragma unroll
    for (int i = 0; i < 4; ++i) {
        int gg = t + i*256, r = gg >> 3, c = gg & 7;
        pa[i] = *reinterpret_cast<const uint4*>(A + (size_t)(row0 + r)*KD + c*8);
    }
    #pragma unroll
    for (int i = 0; i < 2; ++i) {
        int gg = t + i*256, r = gg >> 3, c = gg & 7;
        pb[i] = *reinterpret_cast<const uint4*>(W + (size_t)(n0 + r)*KD + c*8);
    }

    #pragma unroll
    for (int kt = 0; kt < KD; kt += 64) {
        __syncthreads();
        #pragma unroll
        for (int i = 0; i < 4; ++i) {
            int gg = t + i*256, r = gg >> 3, c = gg & 7;
            AsU[r*8 + (c ^ (r & 7))] = pa[i];
        }
        #pragma unroll
        for (int i = 0; i < 2; ++i) {
            int gg = t + i*256, r = gg >> 3, c = gg & 7;
            BsU[r*8 + (c ^ (r & 7))] = pb[i];
        }
        __syncthreads();
        if (kt + 64 < KD) {
            #pragma unroll
            for (int i = 0; i < 4; ++i) {
                int gg = t + i*256, r = gg >> 3, c = gg & 7;
                pa[i] = *reinterpret_cast<const uint4*>(A + (size_t)(row0 + r)*KD + (kt + 64) + c*8);
            }
            #pragma unroll
            for (int i = 0; i < 2; ++i) {
                int gg = t + i*256, r = gg >> 3, c = gg & 7;
                pb[i] = *reinterpret_cast<const uint4*>(W + (size_t)(n0 + r)*KD + (kt + 64) + c*8);
            }
        }
        #pragma unroll
        for (int ks = 0; ks < 2; ++ks) {
            int cg = ks*4 + (lane >> 4);
            bf16x8 af[4], bfr[2];
            #pragma unroll
            for (int m = 0; m < 4; ++m) {
                int ar = wm*64 + m*16 + (lane & 15);
                af[m] = Asv[ar*8 + (cg ^ (ar & 7))];
            }
            #pragma unroll
            for (int nn = 0; nn < 2; ++nn) {
                int br = wn*32 + nn*16 + (lane & 15);
                bfr[nn] = Bsv[br*8 + (cg ^ (br & 7))];
            }
            #pragma unroll
            for (int m = 0; m < 4; ++m)
                #pragma unroll
                for (int nn = 0; nn < 2; ++nn)
                    acc[m][nn] = __builtin_amdgcn_mfma_f32_16x16x32_bf16(af[m], bfr[nn], acc[m][nn], 0, 0, 0);
        }
    }

    // ---- epilogue: bias(+relu) -> LDS f32 tile (pad 68) -> coalesced stores
    __syncthreads();
    #pragma unroll
    for (int m = 0; m < 4; ++m) {
        #pragma unroll
        for (int nn = 0; nn < 2; ++nn) {
            int cc = wn*32 + nn*16 + (lane & 15);
            float bcol = bias[n0 + cc];
            #pragma unroll
            for (int r = 0; r < 4; ++r) {
                int rr = wm*64 + m*16 + (lane >> 4)*4 + r;
                float v = acc[m][nn][r] + bcol;
                if (RELU) v = fmaxf(v, 0.f);
                ctile[rr*68 + cc] = v;
            }
        }
    }
    __syncthreads();
    if (OUTBF) {
        int c8 = (t & 7) * 8;
        #pragma unroll
        for (int rr = t >> 3; rr < 128; rr += 32) {
            const float* src = ctile + rr*68 + c8;
            unsigned us0 = (unsigned)f2bf(src[0]) | ((unsigned)f2bf(src[1]) << 16);
            unsigned us1 = (unsigned)f2bf(src[2]) | ((unsigned)f2bf(src[3]) << 16);
            unsigned us2 = (unsigned)f2bf(src[4]) | ((unsigned)f2bf(src[5]) << 16);
            unsigned us3 = (unsigned)f2bf(src[6]) | ((unsigned)f2bf(src[7]) << 16);
            uint4 uv = { us0, us1, us2, us3 };
            *reinterpret_cast<uint4*>((bf16*)Op + (size_t)(row0 + rr)*Nc + n0 + c8) = uv;
        }
    } else {
        int c4 = (t & 15) * 4;
        #pragma unroll
        for (int rr = t >> 4; rr < 128; rr += 16) {
            float4 v = *reinterpret_cast<const float4*>(ctile + rr*68 + c4);
            *reinterpret_cast<float4*>((float*)Op + (size_t)(row0 + rr)*Nc + n0 + c4) = v;
        }
    }
}

// ---------------- final decoder projection ----------------
__global__ __launch_bounds__(128) void final_kernel(
    const float* __restrict__ X, const float* __restrict__ Wp,
    const float* __restrict__ bp, float* __restrict__ out)
{
    __shared__ float rows[1024];
    int b = blockIdx.x, t = threadIdx.x;
    for (int u = t; u < 1024; u += 128) {
        int g = u >> 8;
        int id = (g == 0) ? 511 : (g == 1) ? 639 : (g == 2) ? 671 : 679;
        rows[u] = X[((size_t)(b*NTOK + id))*DM + (u & 255)];
    }
    __syncthreads();
    if (t < 96) {
        float acc = bp[t];
        #pragma unroll 8
        for (int k = 0; k < 1024; ++k) acc = fmaf(rows[k], Wp[k*96 + t], acc);
        out[b*96 + t] = acc;
    }
}

// ---------------- host launch ----------------
extern "C" void kernel_launch(void* const* d_in, const int* in_sizes, int n_in,
                              void* d_out, int out_size, void* d_ws, size_t ws_size,
                              hipStream_t stream)
{
    const float* x_enc  = (const float*)d_in[0];
    const float* x_mark = (const float*)d_in[1];
    const float* W_val  = (const float*)d_in[2];
    const float* W_time = (const float*)d_in[3];
    const float* b_time = (const float*)d_in[4];
    const float* W_down = (const float*)d_in[5];
    const float* b_down = (const float*)d_in[6];
    const float* W_conv = (const float*)d_in[7];
    const float* b_conv = (const float*)d_in[8];
    const float* bn_g   = (const float*)d_in[9];
    const float* bn_b   = (const float*)d_in[10];
    const float* W_up   = (const float*)d_in[11];
    const float* b_up   = (const float*)d_in[12];
    const float* ln_c_g = (const float*)d_in[13];
    const float* ln_c_b = (const float*)d_in[14];
    const float* Wq     = (const float*)d_in[15];
    const float* bq     = (const float*)d_in[16];
    const float* Wk     = (const float*)d_in[17];
    const float* bk     = (const float*)d_in[18];
    const float* Wv     = (const float*)d_in[19];
    const float* bv     = (const float*)d_in[20];
    const float* Wo     = (const float*)d_in[21];
    const float* bo     = (const float*)d_in[22];
    const float* ln1_g  = (const float*)d_in[23];
    const float* ln1_b  = (const float*)d_in[24];
    const float* W1f    = (const float*)d_in[25];
    const float* b1f    = (const float*)d_in[26];
    const float* W2f    = (const float*)d_in[27];
    const float* b2f    = (const float*)d_in[28];
    const float* ln2_g  = (const float*)d_in[29];
    const float* ln2_b  = (const float*)d_in[30];
    const float* Wp     = (const float*)d_in[31];
    const float* bp     = (const float*)d_in[32];

    const size_t RB = (size_t)NROWS * DM;
    float* ws = (float*)d_ws;
    float* X    = ws;
    float* Pb   = X + RB;
    float* Td   = Pb + RB;
    float* Pool = Td + (size_t)B*SEQ*64;
    bf16* bws   = (bf16*)(Pool + (size_t)B*168*64);
    bf16* Xh   = bws;
    bf16* Qh   = Xh  + RB;
    bf16* Kh   = Qh  + RB;
    bf16* Vh   = Kh  + RB;
    bf16* Obh  = Vh  + RB;
    bf16* Hdh  = Obh + RB;
    bf16* WqT  = Hdh + (size_t)NROWS*FF;
    bf16* WkT  = WqT + 2*65536;
    bf16* WvT  = WkT + 2*65536;
    bf16* WoT  = WvT + 2*65536;
    bf16* W1T  = WoT + 2*65536;
    bf16* W2T  = W1T + 2*131072;
    int*  nbr  = (int*)(W2T + 2*131072);
    int*  ncnt = nbr + NTOK*16;

    WTable tbl;
    for (int l = 0; l < 2; ++l) {
        tbl.d[l*6+0] = { Wq  + (size_t)l*65536,  WqT + (size_t)l*65536,  65536, 8, 256 };
        tbl.d[l*6+1] = { Wk  + (size_t)l*65536,  WkT + (size_t)l*65536,  65536, 8, 256 };
        tbl.d[l*6+2] = { Wv  + (size_t)l*65536,  WvT + (size_t)l*65536,  65536, 8, 256 };
        tbl.d[l*6+3] = { Wo  + (size_t)l*65536,  WoT + (size_t)l*65536,  65536, 8, 256 };
        tbl.d[l*6+4] = { W1f + (size_t)l*131072, W1T + (size_t)l*131072, 131072, 8, 512 };
        tbl.d[l*6+5] = { W2f + (size_t)l*131072, W2T + (size_t)l*131072, 131072, 9, 256 };
    }
    wconv_kernel<<<dim3(512, 12), 256, 0, stream>>>(tbl);

    emb_kernel<<<B*SEQ, 256, 0, stream>>>(x_enc, x_mark, W_val, W_time, b_time, X);
    down_kernel<<<(B*SEQ)/4, 256, 0, stream>>>(X, W_down, b_down, Td);
    conv_kernel<<<B*128, 64, 0, stream>>>(Td, 512, 0,   Pool, 0,   128, W_conv, b_conv, bn_g, bn_b, 0);
    conv_kernel<<<B*32,  64, 0, stream>>>(Pool, 168, 0,  Pool, 128, 32,  W_conv, b_conv, bn_g, bn_b, 1);
    conv_kernel<<<B*8,   64, 0, stream>>>(Pool, 168, 128,Pool, 160, 8,   W_conv, b_conv, bn_g, bn_b, 2);
    up_kernel<<<B*168, 256, 0, stream>>>(Pool, W_up, b_up, X);
    ln_kernel<<<NROWS/4, 256, 0, stream>>>(X, nullptr, ln_c_g, ln_c_b, Xh);
    nbr_kernel<<<11, 64, 0, stream>>>(nbr, ncnt);

    for (int l = 0; l < 2; ++l) {
        const bf16* wqt = WqT + (size_t)l*65536;
        const bf16* wkt = WkT + (size_t)l*65536;
        const bf16* wvt = WvT + (size_t)l*65536;
        const bf16* wot = WoT + (size_t)l*65536;
        const bf16* w1t = W1T + (size_t)l*131072;
        const bf16* w2t = W2T + (size_t)l*131072;
        const float* bq_ = bq + l*DM; const float* bk_ = bk + l*DM;
        const float* bv_ = bv + l*DM; const float* bo_ = bo + l*DM;
        const float* b1_ = b1f + l*FF; const float* b2_ = b2f + l*DM;

        mfma_gemm<256,4,3,false,true><<<2040, 256, 0, stream>>>(
            Xh, wqt, wkt, wvt, bq_, bk_, bv_, Qh, Kh, Vh, 256);
        attn_kernel<<<NROWS, 256, 0, stream>>>(Qh, Kh, Vh, Obh, nbr, ncnt);
        mfma_gemm<256,4,1,false,false><<<680, 256, 0, stream>>>(
            Obh, wot, wot, wot, bo_, bo_, bo_, Pb, Pb, Pb, 256);
        ln_kernel<<<NROWS/4, 256, 0, stream>>>(X, Pb, ln1_g + l*DM, ln1_b + l*DM, Xh);
        mfma_gemm<256,8,1,true,true><<<1360, 256, 0, stream>>>(
            Xh, w1t, w1t, w1t, b1_, b1_, b1_, Hdh, Hdh, Hdh, 512);
        mfma_gemm<512,4,1,false,false><<<680, 256, 0, stream>>>(
            Hdh, w2t, w2t, w2t, b2_, b2_, b2_, Pb, Pb, Pb, 256);
        ln_kernel<<<NROWS/4, 256, 0, stream>>>(X, Pb, ln2_g + l*DM, ln2_b + l*DM, Xh);
    }

    final_kernel<<<B, 128, 0, stream>>>(X, Wp, bp, (float*)d_out);
}

// Round 4
// 607.902 us; speedup vs baseline: 2.0269x; 1.2047x over previous
//
#include <hip/hip_runtime.h>
#include <hip/hip_bf16.h>
#include <math.h>

// ---------------- constants ----------------
#define B 32
#define SEQ 512
#define NTOK 680           // 512+128+32+8
#define DM 256
#define FF 512
#define NROWS (B*NTOK)     // 21760

using bf16x8 = __attribute__((ext_vector_type(8))) short;
using f32x4  = __attribute__((ext_vector_type(4))) float;
typedef __hip_bfloat16 bf16;

__device__ __forceinline__ unsigned short f2bf(float f) {
    union { float f; unsigned u; } x; x.f = f;
    unsigned r = (x.u + 0x7fffu + ((x.u >> 16) & 1u)) >> 16;
    return (unsigned short)r;
}
__device__ __forceinline__ float bfu2f(unsigned short u) {
    union { unsigned u; float f; } x; x.u = ((unsigned)u) << 16;
    return x.f;
}
__device__ __forceinline__ void dotu(unsigned a, unsigned b, float& s) {
    union { unsigned u; float f; } al, ah, bl, bh;
    al.u = a << 16; ah.u = a & 0xffff0000u;
    bl.u = b << 16; bh.u = b & 0xffff0000u;
    s = fmaf(al.f, bl.f, s);
    s = fmaf(ah.f, bh.f, s);
}

// ---------------- embedding (writes fp32 X rows + contiguous bf16 Xe) ----------------
__global__ __launch_bounds__(256) void emb_kernel(
    const float* __restrict__ x_enc, const float* __restrict__ x_mark,
    const float* __restrict__ W_val, const float* __restrict__ W_time,
    const float* __restrict__ b_time, float* __restrict__ X, bf16* __restrict__ Xe)
{
    int bs = blockIdx.x;
    int b = bs >> 9, s = bs & 511;
    int d = threadIdx.x;
    int sm1 = (s + 511) & 511, sp1 = (s + 1) & 511;
    float x0 = x_enc[b*512 + sm1];
    float x1 = x_enc[b*512 + s];
    float x2 = x_enc[b*512 + sp1];
    float val = x0 * W_val[d*3+0] + x1 * W_val[d*3+1] + x2 * W_val[d*3+2];
    const float* mk = &x_mark[(size_t)bs*4];
    float tm = mk[0]*W_time[d] + mk[1]*W_time[256+d] + mk[2]*W_time[512+d] + mk[3]*W_time[768+d];
    int i2 = d & ~1;
    float div = expf((float)i2 * (-9.210340371976184f / 256.0f));
    float ang = (float)s * div;
    float pe = (d & 1) ? cosf(ang) : sinf(ang);
    float out = val + tm + b_time[d] + pe;
    X[((size_t)(b*NTOK + s))*DM + d] = out;
    ((unsigned short*)Xe)[(size_t)bs*DM + d] = f2bf(out);
}

// ---------------- CSCM strided conv + BN affine + ELU ----------------
__global__ __launch_bounds__(64) void conv_kernel(
    const float* __restrict__ in, int inRPB, int inOff,
    float* __restrict__ Pool, int outOff, int Lout,
    const float* __restrict__ W_conv, const float* __restrict__ b_conv,
    const float* __restrict__ bn_g, const float* __restrict__ bn_b, int sc)
{
    __shared__ float lds[256];
    int blk = blockIdx.x;
    int b = blk / Lout, p = blk % Lout;
    int t = threadIdx.x;
    for (int u = t; u < 256; u += 64)
        lds[u] = in[((size_t)(b*inRPB + inOff + p*4 + (u >> 6)))*64 + (u & 63)];
    __syncthreads();
    float acc = b_conv[sc*64 + t];
    const float* w = &W_conv[(size_t)(sc*64 + t)*256];
    #pragma unroll 4
    for (int ci = 0; ci < 64; ++ci) {
        #pragma unroll
        for (int tap = 0; tap < 4; ++tap)
            acc = fmaf(lds[tap*64 + ci], w[ci*4 + tap], acc);
    }
    float v = acc * bn_g[sc*64 + t] + bn_b[sc*64 + t];
    v = v > 0.f ? v : expm1f(v);
    Pool[((size_t)(b*168 + outOff + p))*64 + t] = v;
}

// ---------------- CSCM up-projection ----------------
__global__ __launch_bounds__(256) void up_kernel(
    const float* __restrict__ Pool, const float* __restrict__ W_up,
    const float* __restrict__ b_up, float* __restrict__ X)
{
    __shared__ float row[64];
    int blk = blockIdx.x;
    int b = blk / 168, p = blk % 168;
    int d = threadIdx.x;
    if (d < 64) row[d] = Pool[(size_t)blk*64 + d];
    __syncthreads();
    float acc = b_up[d];
    #pragma unroll 8
    for (int k = 0; k < 64; ++k) acc = fmaf(row[k], W_up[k*256 + d], acc);
    X[((size_t)(b*NTOK + 512 + p))*DM + d] = acc;
}

// ---------------- LayerNorm: one wave per row, float4 lanes ----------------
__global__ __launch_bounds__(256) void ln_kernel(
    float* __restrict__ X, const float* __restrict__ add,
    const float* __restrict__ g, const float* __restrict__ bta,
    bf16* __restrict__ Xh)
{
    int r = blockIdx.x*4 + (threadIdx.x >> 6);
    int lane = threadIdx.x & 63;
    float4 v = ((const float4*)(X + (size_t)r*DM))[lane];
    if (add) {
        float4 a = ((const float4*)(add + (size_t)r*DM))[lane];
        v.x += a.x; v.y += a.y; v.z += a.z; v.w += a.w;
    }
    float s = v.x + v.y + v.z + v.w;
    #pragma unroll
    for (int o = 32; o; o >>= 1) s += __shfl_xor(s, o);
    float mean = s * (1.0f/256.0f);
    float dx = v.x-mean, dy = v.y-mean, dz = v.z-mean, dw = v.w-mean;
    float q = dx*dx + dy*dy + dz*dz + dw*dw;
    #pragma unroll
    for (int o = 32; o; o >>= 1) q += __shfl_xor(q, o);
    float inv = rsqrtf(q*(1.0f/256.0f) + 1e-5f);
    float4 gg = ((const float4*)g)[lane];
    float4 bb = ((const float4*)bta)[lane];
    float4 o4;
    o4.x = dx*inv*gg.x + bb.x;
    o4.y = dy*inv*gg.y + bb.y;
    o4.z = dz*inv*gg.z + bb.z;
    o4.w = dw*inv*gg.w + bb.w;
    ((float4*)(X + (size_t)r*DM))[lane] = o4;
    unsigned u0 = (unsigned)f2bf(o4.x) | ((unsigned)f2bf(o4.y) << 16);
    unsigned u1 = (unsigned)f2bf(o4.z) | ((unsigned)f2bf(o4.w) << 16);
    ((uint2*)(Xh + (size_t)r*DM))[lane] = make_uint2(u0, u1);
}

// ---------------- neighbor lists: closed form ----------------
// sizes {512,128,32,8}, starts {0,512,640,672}; degree = 4 children + <=5 band + 1 parent
__global__ void nbr_kernel(int* __restrict__ nbr, int* __restrict__ ncnt)
{
    int i = blockIdx.x * 64 + threadIdx.x;
    if (i >= NTOK) return;
    const int starts[5] = {0, 512, 640, 672, 680};
    int si = (i < 512) ? 0 : (i < 640) ? 1 : (i < 672) ? 2 : 3;
    int st = starts[si], en = starts[si+1];
    int idx = i - st;
    int cnt = 0;
    if (si >= 1) {
        int cs = starts[si-1] + idx*4;
        #pragma unroll
        for (int c = 0; c < 4; ++c) nbr[i*16 + cnt++] = cs + c;
    }
    int lo = (i-2 > st) ? i-2 : st;
    int hi = (i+2 < en-1) ? i+2 : en-1;
    for (int j = lo; j <= hi; ++j) nbr[i*16 + cnt++] = j;
    if (si <= 2) nbr[i*16 + cnt++] = starts[si+1] + (idx >> 2);
    ncnt[i] = cnt;
}

// ---------------- sparse masked attention, wave-parallel ----------------
__global__ __launch_bounds__(256) void attn_kernel(
    const bf16* __restrict__ Q, const bf16* __restrict__ K,
    const bf16* __restrict__ V, bf16* __restrict__ O,
    const int* __restrict__ nbr, const int* __restrict__ ncnt)
{
    __shared__ float wsm[4][16];
    __shared__ int   jsm[4][16];
    int flat = blockIdx.x;
    int row = (flat & 7) * (NROWS/8) + (flat >> 3);   // XCD-contiguous rows
    int n = row % NTOK, b = row / NTOK;
    int h = threadIdx.x >> 6;
    int lane = threadIdx.x & 63;
    int j = lane >> 2, g = lane & 3;
    int cnt = ncnt[n];
    int nj = (j < cnt) ? nbr[n*16 + j] : n;
    int jr = b*NTOK + nj;

    const uint4* qp = (const uint4*)(Q + (size_t)row*DM + h*64 + g*16);
    const uint4* kp = (const uint4*)(K + (size_t)jr*DM + h*64 + g*16);
    uint4 qa = qp[0], qb = qp[1];
    uint4 ka = kp[0], kb = kp[1];
    float s = 0.f;
    dotu(qa.x, ka.x, s); dotu(qa.y, ka.y, s); dotu(qa.z, ka.z, s); dotu(qa.w, ka.w, s);
    dotu(qb.x, kb.x, s); dotu(qb.y, kb.y, s); dotu(qb.z, kb.z, s); dotu(qb.w, kb.w, s);
    s += __shfl_xor(s, 1);
    s += __shfl_xor(s, 2);
    s *= 0.125f;
    if (j >= cnt) s = -1e30f;
    float m = s;
    #pragma unroll
    for (int o = 4; o < 64; o <<= 1) m = fmaxf(m, __shfl_xor(m, o));
    float w = (j < cnt) ? expf(s - m) : 0.f;
    float den = w;
    #pragma unroll
    for (int o = 4; o < 64; o <<= 1) den += __shfl_xor(den, o);
    if (g == 0) { wsm[h][j] = w / den; jsm[h][j] = jr; }
    __syncthreads();

    float acc = 0.f;
    const unsigned short* Vu = (const unsigned short*)V;
    for (int jj = 0; jj < cnt; ++jj) {
        float wv = wsm[h][jj];
        int rr = jsm[h][jj];
        acc = fmaf(wv, bfu2f(Vu[(size_t)rr*DM + h*64 + lane]), acc);
    }
    ((unsigned short*)O)[(size_t)row*DM + h*64 + lane] = f2bf(acc);
}

// ---------------- weight transpose + bf16 convert: 32x32 LDS tiles ----------------
// dst[n*K + k] = bf16(src[k*N + n]); both sides coalesced
struct WDesc { const float* src; bf16* dst; int K; int N; };
struct WTable { WDesc d[13]; };
__global__ __launch_bounds__(256) void wconv_kernel(WTable tbl)
{
    __shared__ float lds[32][33];
    WDesc ds = tbl.d[blockIdx.y];
    int ntn = ds.N >> 5;
    int ntiles = (ds.K >> 5) * ntn;
    int tile = blockIdx.x;
    if (tile >= ntiles) return;
    int k0 = (tile / ntn) * 32, n0 = (tile % ntn) * 32;
    int t = threadIdx.x;
    int r = t >> 3, c4 = (t & 7) * 4;
    float4 v = *(const float4*)(ds.src + (size_t)(k0 + r)*ds.N + n0 + c4);
    lds[r][c4+0] = v.x; lds[r][c4+1] = v.y; lds[r][c4+2] = v.z; lds[r][c4+3] = v.w;
    __syncthreads();
    unsigned u0 = (unsigned)f2bf(lds[c4+0][r]) | ((unsigned)f2bf(lds[c4+1][r]) << 16);
    unsigned u1 = (unsigned)f2bf(lds[c4+2][r]) | ((unsigned)f2bf(lds[c4+3][r]) << 16);
    *(uint2*)((unsigned short*)ds.dst + (size_t)(n0 + r)*ds.K + k0 + c4) = make_uint2(u0, u1);
}

// ---------------- MFMA bf16 GEMM ----------------
template<int KD, int NY, int NZ, bool RELU, bool OUTBF>
__global__ __launch_bounds__(256) void mfma_gemm(
    const bf16* __restrict__ A,
    const bf16* __restrict__ Wt0, const bf16* __restrict__ Wt1, const bf16* __restrict__ Wt2,
    const float* __restrict__ b0, const float* __restrict__ b1, const float* __restrict__ b2,
    void* __restrict__ O0, void* __restrict__ O1, void* __restrict__ O2,
    int Nc)
{
    __shared__ __align__(16) char smem[34816];   // staging 24KB | ctile 128*68*4
    uint4* AsU = (uint4*)smem;
    uint4* BsU = (uint4*)(smem + 16384);
    const bf16x8* Asv = (const bf16x8*)smem;
    const bf16x8* Bsv = (const bf16x8*)(smem + 16384);
    float* ctile = (float*)smem;

    int t = threadIdx.x;
    int lane = t & 63, wid = t >> 6;
    int wm = wid >> 1, wn = wid & 1;
    int nwg = gridDim.x;
    int wg = (blockIdx.x & 7) * (nwg >> 3) + (blockIdx.x >> 3);
    int xt = wg / (NY*NZ);
    int yz = wg % (NY*NZ);
    int y = yz / NZ, z = yz % NZ;
    int row0 = xt * 128;
    int n0 = y * 64;
    const bf16* W = (z == 0) ? Wt0 : (z == 1) ? Wt1 : Wt2;
    const float* bias = (z == 0) ? b0 : (z == 1) ? b1 : b2;
    void* Op = (z == 0) ? O0 : (z == 1) ? O1 : O2;

    f32x4 acc[4][2];
    #pragma unroll
    for (int i = 0; i < 4; ++i)
        #pragma unroll
        for (int jn = 0; jn < 2; ++jn)
            #pragma unroll
            for (int r = 0; r < 4; ++r) acc[i][jn][r] = 0.f;

    uint4 pa[4], pb[2];
    #pragma unroll
    for (int i = 0; i < 4; ++i) {
        int gg = t + i*256, r = gg >> 3, c = gg & 7;
        pa[i] = *reinterpret_cast<const uint4*>(A + (size_t)(row0 + r)*KD + c*8);
    }
    #pragma unroll
    for (int i = 0; i < 2; ++i) {
        int gg = t + i*256, r = gg >> 3, c = gg & 7;
        pb[i] = *reinterpret_cast<const uint4*>(W + (size_t)(n0 + r)*KD + c*8);
    }

    #pragma unroll
    for (int kt = 0; kt < KD; kt += 64) {
        __syncthreads();
        #pragma unroll
        for (int i = 0; i < 4; ++i) {
            int gg = t + i*256, r = gg >> 3, c = gg & 7;
            AsU[r*8 + (c ^ (r & 7))] = pa[i];
        }
        #pragma unroll
        for (int i = 0; i < 2; ++i) {
            int gg = t + i*256, r = gg >> 3, c = gg & 7;
            BsU[r*8 + (c ^ (r & 7))] = pb[i];
        }
        __syncthreads();
        if (kt + 64 < KD) {
            #pragma unroll
            for (int i = 0; i < 4; ++i) {
                int gg = t + i*256, r = gg >> 3, c = gg & 7;
                pa[i] = *reinterpret_cast<const uint4*>(A + (size_t)(row0 + r)*KD + (kt + 64) + c*8);
            }
            #pragma unroll
            for (int i = 0; i < 2; ++i) {
                int gg = t + i*256, r = gg >> 3, c = gg & 7;
                pb[i] = *reinterpret_cast<const uint4*>(W + (size_t)(n0 + r)*KD + (kt + 64) + c*8);
            }
        }
        #pragma unroll
        for (int ks = 0; ks < 2; ++ks) {
            int cg = ks*4 + (lane >> 4);
            bf16x8 af[4], bfr[2];
            #pragma unroll
            for (int m = 0; m < 4; ++m) {
                int ar = wm*64 + m*16 + (lane & 15);
                af[m] = Asv[ar*8 + (cg ^ (ar & 7))];
            }
            #pragma unroll
            for (int nn = 0; nn < 2; ++nn) {
                int br = wn*32 + nn*16 + (lane & 15);
                bfr[nn] = Bsv[br*8 + (cg ^ (br & 7))];
            }
            #pragma unroll
            for (int m = 0; m < 4; ++m)
                #pragma unroll
                for (int nn = 0; nn < 2; ++nn)
                    acc[m][nn] = __builtin_amdgcn_mfma_f32_16x16x32_bf16(af[m], bfr[nn], acc[m][nn], 0, 0, 0);
        }
    }

    __syncthreads();
    #pragma unroll
    for (int m = 0; m < 4; ++m) {
        #pragma unroll
        for (int nn = 0; nn < 2; ++nn) {
            int cc = wn*32 + nn*16 + (lane & 15);
            float bcol = bias[n0 + cc];
            #pragma unroll
            for (int r = 0; r < 4; ++r) {
                int rr = wm*64 + m*16 + (lane >> 4)*4 + r;
                float v = acc[m][nn][r] + bcol;
                if (RELU) v = fmaxf(v, 0.f);
                ctile[rr*68 + cc] = v;
            }
        }
    }
    __syncthreads();
    if (OUTBF) {
        int c8 = (t & 7) * 8;
        #pragma unroll
        for (int rr = t >> 3; rr < 128; rr += 32) {
            const float* src = ctile + rr*68 + c8;
            unsigned us0 = (unsigned)f2bf(src[0]) | ((unsigned)f2bf(src[1]) << 16);
            unsigned us1 = (unsigned)f2bf(src[2]) | ((unsigned)f2bf(src[3]) << 16);
            unsigned us2 = (unsigned)f2bf(src[4]) | ((unsigned)f2bf(src[5]) << 16);
            unsigned us3 = (unsigned)f2bf(src[6]) | ((unsigned)f2bf(src[7]) << 16);
            uint4 uv = { us0, us1, us2, us3 };
            *reinterpret_cast<uint4*>((bf16*)Op + (size_t)(row0 + rr)*Nc + n0 + c8) = uv;
        }
    } else {
        int c4 = (t & 15) * 4;
        #pragma unroll
        for (int rr = t >> 4; rr < 128; rr += 16) {
            float4 v = *reinterpret_cast<const float4*>(ctile + rr*68 + c4);
            *reinterpret_cast<float4*>((float*)Op + (size_t)(row0 + rr)*Nc + n0 + c4) = v;
        }
    }
}

// ---------------- final decoder projection ----------------
__global__ __launch_bounds__(128) void final_kernel(
    const float* __restrict__ X, const float* __restrict__ Wp,
    const float* __restrict__ bp, float* __restrict__ out)
{
    __shared__ float rows[1024];
    int b = blockIdx.x, t = threadIdx.x;
    for (int u = t; u < 1024; u += 128) {
        int g = u >> 8;
        int id = (g == 0) ? 511 : (g == 1) ? 639 : (g == 2) ? 671 : 679;
        rows[u] = X[((size_t)(b*NTOK + id))*DM + (u & 255)];
    }
    __syncthreads();
    if (t < 96) {
        float acc = bp[t];
        #pragma unroll 8
        for (int k = 0; k < 1024; ++k) acc = fmaf(rows[k], Wp[k*96 + t], acc);
        out[b*96 + t] = acc;
    }
}

// ---------------- host launch ----------------
extern "C" void kernel_launch(void* const* d_in, const int* in_sizes, int n_in,
                              void* d_out, int out_size, void* d_ws, size_t ws_size,
                              hipStream_t stream)
{
    const float* x_enc  = (const float*)d_in[0];
    const float* x_mark = (const float*)d_in[1];
    const float* W_val  = (const float*)d_in[2];
    const float* W_time = (const float*)d_in[3];
    const float* b_time = (const float*)d_in[4];
    const float* W_down = (const float*)d_in[5];
    const float* b_down = (const float*)d_in[6];
    const float* W_conv = (const float*)d_in[7];
    const float* b_conv = (const float*)d_in[8];
    const float* bn_g   = (const float*)d_in[9];
    const float* bn_b   = (const float*)d_in[10];
    const float* W_up   = (const float*)d_in[11];
    const float* b_up   = (const float*)d_in[12];
    const float* ln_c_g = (const float*)d_in[13];
    const float* ln_c_b = (const float*)d_in[14];
    const float* Wq     = (const float*)d_in[15];
    const float* bq     = (const float*)d_in[16];
    const float* Wk     = (const float*)d_in[17];
    const float* bk     = (const float*)d_in[18];
    const float* Wv     = (const float*)d_in[19];
    const float* bv     = (const float*)d_in[20];
    const float* Wo     = (const float*)d_in[21];
    const float* bo     = (const float*)d_in[22];
    const float* ln1_g  = (const float*)d_in[23];
    const float* ln1_b  = (const float*)d_in[24];
    const float* W1f    = (const float*)d_in[25];
    const float* b1f    = (const float*)d_in[26];
    const float* W2f    = (const float*)d_in[27];
    const float* b2f    = (const float*)d_in[28];
    const float* ln2_g  = (const float*)d_in[29];
    const float* ln2_b  = (const float*)d_in[30];
    const float* Wp     = (const float*)d_in[31];
    const float* bp     = (const float*)d_in[32];

    const size_t RB = (size_t)NROWS * DM;
    float* ws = (float*)d_ws;
    float* X    = ws;
    float* Pb   = X + RB;
    float* Td   = Pb + RB;                     // 16384*64 f32
    float* Pool = Td + (size_t)B*SEQ*64;
    bf16* bws   = (bf16*)(Pool + (size_t)B*168*64);
    bf16* Xh   = bws;
    bf16* Qh   = Xh  + RB;
    bf16* Kh   = Qh  + RB;
    bf16* Vh   = Kh  + RB;
    bf16* Obh  = Vh  + RB;
    bf16* Hdh  = Obh + RB;
    bf16* Xe   = Hdh + (size_t)NROWS*FF;       // 16384*256 bf16 (contiguous emb)
    bf16* WqT  = Xe  + (size_t)B*SEQ*DM;
    bf16* WkT  = WqT + 2*65536;
    bf16* WvT  = WkT + 2*65536;
    bf16* WoT  = WvT + 2*65536;
    bf16* W1T  = WoT + 2*65536;
    bf16* W2T  = W1T + 2*131072;
    bf16* WdT  = W2T + 2*131072;               // [64][256]
    int*  nbr  = (int*)(WdT + 64*256);
    int*  ncnt = nbr + NTOK*16;

    WTable tbl;
    for (int l = 0; l < 2; ++l) {
        tbl.d[l*6+0] = { Wq  + (size_t)l*65536,  WqT + (size_t)l*65536,  256, 256 };
        tbl.d[l*6+1] = { Wk  + (size_t)l*65536,  WkT + (size_t)l*65536,  256, 256 };
        tbl.d[l*6+2] = { Wv  + (size_t)l*65536,  WvT + (size_t)l*65536,  256, 256 };
        tbl.d[l*6+3] = { Wo  + (size_t)l*65536,  WoT + (size_t)l*65536,  256, 256 };
        tbl.d[l*6+4] = { W1f + (size_t)l*131072, W1T + (size_t)l*131072, 256, 512 };
        tbl.d[l*6+5] = { W2f + (size_t)l*131072, W2T + (size_t)l*131072, 512, 256 };
    }
    tbl.d[12] = { W_down, WdT, 256, 64 };
    wconv_kernel<<<dim3(128, 13), 256, 0, stream>>>(tbl);

    emb_kernel<<<B*SEQ, 256, 0, stream>>>(x_enc, x_mark, W_val, W_time, b_time, X, Xe);
    // down-projection via MFMA: Td[16384,64] = Xe[16384,256] @ W_down + b_down
    mfma_gemm<256,1,1,false,false><<<128, 256, 0, stream>>>(
        Xe, WdT, WdT, WdT, b_down, b_down, b_down, Td, Td, Td, 64);
    conv_kernel<<<B*128, 64, 0, stream>>>(Td, 512, 0,   Pool, 0,   128, W_conv, b_conv, bn_g, bn_b, 0);
    conv_kernel<<<B*32,  64, 0, stream>>>(Pool, 168, 0,  Pool, 128, 32,  W_conv, b_conv, bn_g, bn_b, 1);
    conv_kernel<<<B*8,   64, 0, stream>>>(Pool, 168, 128,Pool, 160, 8,   W_conv, b_conv, bn_g, bn_b, 2);
    up_kernel<<<B*168, 256, 0, stream>>>(Pool, W_up, b_up, X);
    ln_kernel<<<NROWS/4, 256, 0, stream>>>(X, nullptr, ln_c_g, ln_c_b, Xh);
    nbr_kernel<<<11, 64, 0, stream>>>(nbr, ncnt);

    for (int l = 0; l < 2; ++l) {
        const bf16* wqt = WqT + (size_t)l*65536;
        const bf16* wkt = WkT + (size_t)l*65536;
        const bf16* wvt = WvT + (size_t)l*65536;
        const bf16* wot = WoT + (size_t)l*65536;
        const bf16* w1t = W1T + (size_t)l*131072;
        const bf16* w2t = W2T + (size_t)l*131072;
        const float* bq_ = bq + l*DM; const float* bk_ = bk + l*DM;
        const float* bv_ = bv + l*DM; const float* bo_ = bo + l*DM;
        const float* b1_ = b1f + l*FF; const float* b2_ = b2f + l*DM;

        mfma_gemm<256,4,3,false,true><<<2040, 256, 0, stream>>>(
            Xh, wqt, wkt, wvt, bq_, bk_, bv_, Qh, Kh, Vh, 256);
        attn_kernel<<<NROWS, 256, 0, stream>>>(Qh, Kh, Vh, Obh, nbr, ncnt);
        mfma_gemm<256,4,1,false,false><<<680, 256, 0, stream>>>(
            Obh, wot, wot, wot, bo_, bo_, bo_, Pb, Pb, Pb, 256);
        ln_kernel<<<NROWS/4, 256, 0, stream>>>(X, Pb, ln1_g + l*DM, ln1_b + l*DM, Xh);
        mfma_gemm<256,8,1,true,true><<<1360, 256, 0, stream>>>(
            Xh, w1t, w1t, w1t, b1_, b1_, b1_, Hdh, Hdh, Hdh, 512);
        mfma_gemm<512,4,1,false,false><<<680, 256, 0, stream>>>(
            Hdh, w2t, w2t, w2t, b2_, b2_, b2_, Pb, Pb, Pb, 256);
        ln_kernel<<<NROWS/4, 256, 0, stream>>>(X, Pb, ln2_g + l*DM, ln2_b + l*DM, Xh);
    }

    final_kernel<<<B, 128, 0, stream>>>(X, Wp, bp, (float*)d_out);
}